// Round 1
// baseline (140.071 us; speedup 1.0000x reference)
//
#include <hip/hip_runtime.h>
#include <hip/hip_bf16.h>
#include <math.h>

#define M_ROWS 65536
#define NSPLINE 32
#define BM 64            // rows per block
#define WROWS 16         // rows per wave
#define GROUP 4          // splines per iteration
#define NITER (NSPLINE / GROUP)   // 8
#define YS 34            // fp32 words per task slot (34%32=2 -> 2-way alias, free; 8B-aligned)
#define WB_ELEMS (32 * 3 * 2 * 64 * 8)   // 98304 fp16

typedef __attribute__((ext_vector_type(8))) _Float16 half8;
typedef __attribute__((ext_vector_type(4))) float floatx4;

// Accurate-enough softplus: log(1+e^t) = t/2 + log(2*cosh(t/2)).
// Even Taylor in u=t^2 through u^4; |err| <= ~5e-6 for |t| <= 1.1.
// Exact log1pf fallback outside (P ~ 1e-7 per eval).  [R5/R8-proven]
__device__ __forceinline__ float softplus_fast(float t) {
    float u = t * t;
    if (u > 1.21f) return log1pf(__expf(t));   // rare, exact
    float p = fmaf(u, -2.6352e-5f, 3.4722222e-4f);
    p = fmaf(u, p, -5.2083333e-3f);
    p = fmaf(u, p, 0.125f);
    p = fmaf(u, p, 0.69314718f);
    return fmaf(t, 0.5f, p);
}

// ---------------------------------------------------------------------------
// Pack W (48x1056 fp32) + bias (1056) into MFMA fragment layout, fp16.
// WH[sp][t][half][lane][j]:
//   k  = half*32 + (lane>>4)*8 + j   (k<48: W[k][col]; k==48: bias; else 0)
//   cl = t*16 + (lane&15), col = sp*33+cl  (cl>=33 -> zero pad)
// Used as the A operand (m = param = lane&15).  [unchanged from R10]
// ---------------------------------------------------------------------------
__global__ void pack_W(const float* __restrict__ W, const float* __restrict__ b,
                       _Float16* __restrict__ WH) {
    int idx = blockIdx.x * 256 + threadIdx.x;     // < 98304
    int j    = idx & 7;
    int lane = (idx >> 3) & 63;
    int half = (idx >> 9) & 1;
    int tmp  = idx >> 10;
    int t    = tmp % 3;
    int sp   = tmp / 3;
    int k  = half * 32 + ((lane >> 4) << 3) + j;
    int cl = t * 16 + (lane & 15);
    float v = 0.0f;
    if (cl < 33 && k <= 48) {
        int col = sp * 33 + cl;
        v = (k < 48) ? W[k * 1056 + col] : b[col];
    }
    WH[idx] = (_Float16)v;
}

// ---------------------------------------------------------------------------
// R11: SOFTWARE-PIPELINED across spline groups. The old body was a serial
// chain per group g: WH-load(~200cy) -> MFMA -> ds_write -> ds_read ->
// spline VALU(~640cy); VALU only busy 56% because every wave stalls on the
// same chain in phase. Now GEMM(g+1) (loads+MFMA+LDS writes into the
// wave-private region whose g-data already lives in pv registers) is issued
// BEFORE spline(g); the spline's ~640 VALU cycles hide the GEMM chain, and
// the trailing pv-read(g+1) hides under the NEXT iteration's GEMM issue.
// Same per-wave in-order-DS correctness argument as the R10 barrier-free
// design (writes of g+1 issue after reads of g in program order).
// Spline numerics byte-identical to R8/R10 (absmax 0.015625).
// The q==0 param-32 store became an address-select store into the YS pad
// slot (33) so the GEMM chunk is one branch-free scheduling region.
// ---------------------------------------------------------------------------

#define GEMM_GROUP(GIDX)                                                      \
    {                                                                         \
      _Pragma("unroll")                                                       \
      for (int sp = 0; sp < GROUP; ++sp) {                                    \
        const int spg = (GIDX) * GROUP + sp;                                  \
        const int task = sp * 16 + cc;                                        \
        _Pragma("unroll")                                                     \
        for (int t = 0; t < 3; ++t) {                                         \
          const half8* p = (const half8*)WH + (size_t)(spg * 3 + t) * 128 + lane; \
          half8 b0 = p[0];                                                    \
          half8 b1 = p[64];                                                   \
          floatx4 acc = {0.f, 0.f, 0.f, 0.f};                                 \
          acc = __builtin_amdgcn_mfma_f32_16x16x32_f16(b0, a0, acc, 0, 0, 0); \
          acc = __builtin_amdgcn_mfma_f32_16x16x32_f16(b1, a1, acc, 0, 0, 0); \
          if (t < 2) {                                                        \
            float* dst = lds_wv + task * YS + t * 16 + q * 4;                 \
            *(float2*)dst       = make_float2(acc[0], acc[1]);                \
            *(float2*)(dst + 2) = make_float2(acc[2], acc[3]);                \
          } else {                                                            \
            /* param 32 from q==0; q!=0 lanes dump into pad slot 33 (junk) */ \
            lds_wv[task * YS + 32 + (q != 0)] = acc[0];                       \
          }                                                                   \
        }                                                                     \
      }                                                                       \
    }

#define READ_PV()                                                             \
    {                                                                         \
      const float* my = lds_wv + lane * YS;                                   \
      _Pragma("unroll")                                                       \
      for (int i = 0; i < 16; ++i) {                                          \
        float2 v = *(const float2*)(my + 2 * i);                              \
        pv[2 * i] = v.x; pv[2 * i + 1] = v.y;                                 \
      }                                                                       \
      pv[32] = my[32];                                                        \
    }

#define SPLINE(GIDX, INVAL)                                                   \
    {                                                                         \
      const int n = (GIDX) * GROUP + q;                                       \
      const float in = (INVAL);                                               \
      float wd[16];                                                           \
      float sew = 0.f;                                                        \
      _Pragma("unroll")                                                       \
      for (int i = 0; i < 16; ++i) {                                          \
        float e = __expf(pv[17 + i]);                                         \
        wd[i] = e; sew += e;                                                  \
      }                                                                       \
      const float inv_sew = 0.984f / sew;        /* (1 - 16*MIN_BW)/sum */    \
      _Pragma("unroll")                                                       \
      for (int i = 0; i < 16; ++i) wd[i] = 0.001f + wd[i] * inv_sew;          \
      float h[17];                                                            \
      _Pragma("unroll")                                                       \
      for (int i = 0; i < 17; ++i)                                            \
        h[i] = softplus_fast(pv[i]) + 0.001f;                                 \
      float area = 0.f;                                                       \
      _Pragma("unroll")                                                       \
      for (int i = 0; i < 16; ++i) area += (h[i] + h[i + 1]) * 0.5f * wd[i];  \
      const float inv_area = 0.999f / area;      /* (1 - MIN_BH)/area */      \
      _Pragma("unroll")                                                       \
      for (int i = 0; i < 17; ++i) h[i] = 0.001f + h[i] * inv_area;           \
      float loc = 0.f, cdfl = 0.f;                                            \
      float sel_loc = 0.f, sel_w = wd[0], sel_cdf = 0.f;                      \
      float sel_lh = h[0], sel_rh = h[1];                                     \
      _Pragma("unroll")                                                       \
      for (int bn = 1; bn < 16; ++bn) {                                       \
        cdfl = fmaf((h[bn - 1] + h[bn]) * 0.5f, wd[bn - 1], cdfl);            \
        loc += wd[bn - 1];                                                    \
        if (in >= loc) {                        /* monotone: last true wins */\
          sel_loc = loc; sel_w = wd[bn]; sel_cdf = cdfl;                      \
          sel_lh = h[bn]; sel_rh = h[bn + 1];                                 \
        }                                                                     \
      }                                                                       \
      const float alpha = (in - sel_loc) / sel_w;                             \
      const float dh    = sel_rh - sel_lh;                                    \
      float o = ((0.5f * dh * sel_w) * alpha + sel_lh * sel_w) * alpha + sel_cdf; \
      o = fminf(fmaxf(o, 0.0f), 1.0f);                                        \
      out[(size_t)(row_base + cc) * 64 + 32 + n] = o;                         \
      ld_acc += __logf(fmaf(alpha, dh, sel_lh));                              \
    }

__global__ void __launch_bounds__(256) fused_kernel(
    const float* __restrict__ z, const float* __restrict__ c,
    const _Float16* __restrict__ WH, float* __restrict__ out)
{
    __shared__ float lds_y[4 * 64 * YS];         // 34816 B

    const int tid  = threadIdx.x;
    const int w    = tid >> 6;
    const int lane = tid & 63;
    const int q    = lane >> 4;        // quad 0..3
    const int cc   = lane & 15;
    const int row_base = blockIdx.x * BM + w * WROWS;
    float* lds_wv = lds_y + w * (64 * YS);

    // ---- z2 passthrough: out[:, :32] = z[:, 32:64] for this wave's rows ----
    #pragma unroll
    for (int it = 0; it < 2; ++it) {
        int idx = it * 64 + lane;                 // 0..127 = 16 rows x 8 float4
        int rr  = row_base + (idx >> 3);
        int v4  = idx & 7;
        float4 val = *(const float4*)(z + (size_t)rr * 64 + 32 + v4 * 4);
        *(float4*)(out + (size_t)rr * 64 + v4 * 4) = val;
    }

    // ---- z2c fragments (fp16, persist): the B operand ---------------------
    // B[k=(q*8+j)][n=cc] = z2c[row cc][k]
    half8 a0, a1;
    {
        const float* zr = z + (size_t)(row_base + cc) * 64 + 32;
        float4 v0 = *(const float4*)(zr + q * 8);
        float4 v1 = *(const float4*)(zr + q * 8 + 4);
        a0[0]=(_Float16)v0.x; a0[1]=(_Float16)v0.y;
        a0[2]=(_Float16)v0.z; a0[3]=(_Float16)v0.w;
        a0[4]=(_Float16)v1.x; a0[5]=(_Float16)v1.y;
        a0[6]=(_Float16)v1.z; a0[7]=(_Float16)v1.w;
        if (q < 2) {
            const float* cr = c + (size_t)(row_base + cc) * 16 + q * 8;
            float4 u0 = *(const float4*)cr;
            float4 u1 = *(const float4*)(cr + 4);
            a1[0]=(_Float16)u0.x; a1[1]=(_Float16)u0.y;
            a1[2]=(_Float16)u0.z; a1[3]=(_Float16)u0.w;
            a1[4]=(_Float16)u1.x; a1[5]=(_Float16)u1.y;
            a1[6]=(_Float16)u1.z; a1[7]=(_Float16)u1.w;
        } else {
            #pragma unroll
            for (int j = 0; j < 8; ++j) a1[j] = (_Float16)0.0f;
            if (q == 2) a1[0] = (_Float16)1.0f;   // k=48 bias row
        }
    }

    // z1 base for this lane's spline inputs: z[row cc][n = g*4 + q]
    const float* z1p = z + (size_t)(row_base + cc) * 64 + q;

    float pv[33];

    // ---- prologue: GEMM group 0 -> LDS -> pv registers (one exposed chain)
    GEMM_GROUP(0);
    READ_PV();

    float ld_acc = 0.0f;

    // ---- pipelined main loop: GEMM(g+1) overlaps spline(g) ----------------
    #pragma unroll 1
    for (int g = 0; g < NITER - 1; ++g) {
        const float in_g = z1p[g * 4];   // hot L1/L2 line; issues early
        GEMM_GROUP(g + 1);               // loads+MFMA+ds_write, independent of pv
        SPLINE(g, in_g);                 // pure VALU from registers, hides GEMM
        READ_PV();                       // after writes (in-order DS); latency
                                         // hides under next iter's GEMM issue
    }
    {
        const float in_l = z1p[(NITER - 1) * 4];
        SPLINE(NITER - 1, in_l);
    }

    // ---- logdet: lanes {cc, cc+16, cc+32, cc+48} hold row cc's partials ---
    ld_acc += __shfl_down(ld_acc, 32, 64);
    ld_acc += __shfl_down(ld_acc, 16, 64);
    if (q == 0)
        out[(size_t)M_ROWS * 64 + row_base + cc] = ld_acc;
}

extern "C" void kernel_launch(void* const* d_in, const int* in_sizes, int n_in,
                              void* d_out, int out_size, void* d_ws, size_t ws_size,
                              hipStream_t stream) {
    const float* c = (const float*)d_in[0];   // (M, 16)
    const float* z = (const float*)d_in[1];   // (M, 64)
    const float* W = (const float*)d_in[2];   // (48, 1056)
    const float* b = (const float*)d_in[3];   // (1056,)
    float* out = (float*)d_out;               // M*64 (x) then M (logdet)
    _Float16* WH = (_Float16*)d_ws;           // 98304 fp16 = 192 KiB

    pack_W<<<WB_ELEMS / 256, 256, 0, stream>>>(W, b, WH);
    fused_kernel<<<M_ROWS / BM, 256, 0, stream>>>(z, c, WH, out);
}

// Round 2
// 116.375 us; speedup vs baseline: 1.2036x; 1.2036x over previous
//
#include <hip/hip_runtime.h>
#include <hip/hip_bf16.h>
#include <math.h>

#define M_ROWS 65536
#define NSPLINE 32
#define BM 64            // rows per block
#define WROWS 16         // rows per wave
#define GROUP 4          // splines per iteration
#define NITER (NSPLINE / GROUP)   // 8
#define YS 34            // fp32 words per task slot (34%32=2 -> 2-way alias, free; 8B-aligned)
#define WB_ELEMS (32 * 3 * 2 * 64 * 8)   // 98304 fp16

typedef __attribute__((ext_vector_type(8))) _Float16 half8;
typedef __attribute__((ext_vector_type(4))) float floatx4;

// Accurate-enough softplus: log(1+e^t) = t/2 + log(2*cosh(t/2)).
// Even Taylor in u=t^2 through u^4; |err| <= ~5e-6 for |t| <= 1.1.
// Exact log1pf fallback outside (P ~ 1e-7 per eval).  [R5/R8-proven]
__device__ __forceinline__ float softplus_fast(float t) {
    float u = t * t;
    if (u > 1.21f) return log1pf(__expf(t));   // rare, exact
    float p = fmaf(u, -2.6352e-5f, 3.4722222e-4f);
    p = fmaf(u, p, -5.2083333e-3f);
    p = fmaf(u, p, 0.125f);
    p = fmaf(u, p, 0.69314718f);
    return fmaf(t, 0.5f, p);
}

// ---------------------------------------------------------------------------
// Pack W (48x1056 fp32) + bias (1056) into MFMA fragment layout, fp16.
// WH[sp][t][half][lane][j]:
//   k  = half*32 + (lane>>4)*8 + j   (k<48: W[k][col]; k==48: bias; else 0)
//   cl = t*16 + (lane&15), col = sp*33+cl  (cl>=33 -> zero pad)
// Used as the A operand (m = param = lane&15).  [unchanged from R10]
// ---------------------------------------------------------------------------
__global__ void pack_W(const float* __restrict__ W, const float* __restrict__ b,
                       _Float16* __restrict__ WH) {
    int idx = blockIdx.x * 256 + threadIdx.x;     // < 98304
    int j    = idx & 7;
    int lane = (idx >> 3) & 63;
    int half = (idx >> 9) & 1;
    int tmp  = idx >> 10;
    int t    = tmp % 3;
    int sp   = tmp / 3;
    int k  = half * 32 + ((lane >> 4) << 3) + j;
    int cl = t * 16 + (lane & 15);
    float v = 0.0f;
    if (cl < 33 && k <= 48) {
        int col = sp * 33 + cl;
        v = (k < 48) ? W[k * 1056 + col] : b[col];
    }
    WH[idx] = (_Float16)v;
}

// ---------------------------------------------------------------------------
// R12: software pipeline (GEMM(g+1) issued before SPLINE(g)) with R11's two
// measured defects fixed:
//  (1) t==2 store is exec-masked q==0 again. R11's pad-slot dump put 3 lanes
//      on the SAME address per odd bank -> +16 conflict cycles/store
//      (delta was exactly 2^21 = 16 x 131072 stores).
//  (2) __launch_bounds__(256, 4): LDS (34816B) caps occupancy at 4 blocks/CU
//      = 4 waves/SIMD anyway, so let the allocator use the full 128-VGPR
//      budget instead of strangling the pipelined schedule at a 64-reg
//      (8-wave) target, which serialized the WH loads (R11: VGPR 76,
//      VALUBusy 37%).
// Correctness as R10/R11: each wave's LDS region is private; per-wave
// in-order DS + compiler lgkmcnt waits order write(g+1) before read(g+1),
// and SPLINE(g) consumes pv registers loaded before the writes were issued.
// Spline numerics byte-identical to R8/R10 (absmax 0.015625).
// ---------------------------------------------------------------------------

#define GEMM_GROUP(GIDX)                                                      \
    {                                                                         \
      _Pragma("unroll")                                                       \
      for (int sp = 0; sp < GROUP; ++sp) {                                    \
        const int spg = (GIDX) * GROUP + sp;                                  \
        const int task = sp * 16 + cc;                                        \
        _Pragma("unroll")                                                     \
        for (int t = 0; t < 3; ++t) {                                         \
          const half8* p = (const half8*)WH + (size_t)(spg * 3 + t) * 128 + lane; \
          half8 b0 = p[0];                                                    \
          half8 b1 = p[64];                                                   \
          floatx4 acc = {0.f, 0.f, 0.f, 0.f};                                 \
          acc = __builtin_amdgcn_mfma_f32_16x16x32_f16(b0, a0, acc, 0, 0, 0); \
          acc = __builtin_amdgcn_mfma_f32_16x16x32_f16(b1, a1, acc, 0, 0, 0); \
          if (t < 2) {                                                        \
            float* dst = lds_wv + task * YS + t * 16 + q * 4;                 \
            *(float2*)dst       = make_float2(acc[0], acc[1]);                \
            *(float2*)(dst + 2) = make_float2(acc[2], acc[3]);                \
          } else if (q == 0) {                                                \
            lds_wv[task * YS + 32] = acc[0];  /* param 32 only */             \
          }                                                                   \
        }                                                                     \
      }                                                                       \
    }

#define READ_PV()                                                             \
    {                                                                         \
      const float* my = lds_wv + lane * YS;                                   \
      _Pragma("unroll")                                                       \
      for (int i = 0; i < 16; ++i) {                                          \
        float2 v = *(const float2*)(my + 2 * i);                              \
        pv[2 * i] = v.x; pv[2 * i + 1] = v.y;                                 \
      }                                                                       \
      pv[32] = my[32];                                                        \
    }

#define SPLINE(GIDX, INVAL)                                                   \
    {                                                                         \
      const int n = (GIDX) * GROUP + q;                                       \
      const float in = (INVAL);                                               \
      float wd[16];                                                           \
      float sew = 0.f;                                                        \
      _Pragma("unroll")                                                       \
      for (int i = 0; i < 16; ++i) {                                          \
        float e = __expf(pv[17 + i]);                                         \
        wd[i] = e; sew += e;                                                  \
      }                                                                       \
      const float inv_sew = 0.984f / sew;        /* (1 - 16*MIN_BW)/sum */    \
      _Pragma("unroll")                                                       \
      for (int i = 0; i < 16; ++i) wd[i] = 0.001f + wd[i] * inv_sew;          \
      float h[17];                                                            \
      _Pragma("unroll")                                                       \
      for (int i = 0; i < 17; ++i)                                            \
        h[i] = softplus_fast(pv[i]) + 0.001f;                                 \
      float area = 0.f;                                                       \
      _Pragma("unroll")                                                       \
      for (int i = 0; i < 16; ++i) area += (h[i] + h[i + 1]) * 0.5f * wd[i];  \
      const float inv_area = 0.999f / area;      /* (1 - MIN_BH)/area */      \
      _Pragma("unroll")                                                       \
      for (int i = 0; i < 17; ++i) h[i] = 0.001f + h[i] * inv_area;           \
      float loc = 0.f, cdfl = 0.f;                                            \
      float sel_loc = 0.f, sel_w = wd[0], sel_cdf = 0.f;                      \
      float sel_lh = h[0], sel_rh = h[1];                                     \
      _Pragma("unroll")                                                       \
      for (int bn = 1; bn < 16; ++bn) {                                       \
        cdfl = fmaf((h[bn - 1] + h[bn]) * 0.5f, wd[bn - 1], cdfl);            \
        loc += wd[bn - 1];                                                    \
        if (in >= loc) {                        /* monotone: last true wins */\
          sel_loc = loc; sel_w = wd[bn]; sel_cdf = cdfl;                      \
          sel_lh = h[bn]; sel_rh = h[bn + 1];                                 \
        }                                                                     \
      }                                                                       \
      const float alpha = (in - sel_loc) / sel_w;                             \
      const float dh    = sel_rh - sel_lh;                                    \
      float o = ((0.5f * dh * sel_w) * alpha + sel_lh * sel_w) * alpha + sel_cdf; \
      o = fminf(fmaxf(o, 0.0f), 1.0f);                                        \
      out[(size_t)(row_base + cc) * 64 + 32 + n] = o;                         \
      ld_acc += __logf(fmaf(alpha, dh, sel_lh));                              \
    }

__global__ void __launch_bounds__(256, 4) fused_kernel(
    const float* __restrict__ z, const float* __restrict__ c,
    const _Float16* __restrict__ WH, float* __restrict__ out)
{
    __shared__ float lds_y[4 * 64 * YS];         // 34816 B

    const int tid  = threadIdx.x;
    const int w    = tid >> 6;
    const int lane = tid & 63;
    const int q    = lane >> 4;        // quad 0..3
    const int cc   = lane & 15;
    const int row_base = blockIdx.x * BM + w * WROWS;
    float* lds_wv = lds_y + w * (64 * YS);

    // ---- z2 passthrough: out[:, :32] = z[:, 32:64] for this wave's rows ----
    #pragma unroll
    for (int it = 0; it < 2; ++it) {
        int idx = it * 64 + lane;                 // 0..127 = 16 rows x 8 float4
        int rr  = row_base + (idx >> 3);
        int v4  = idx & 7;
        float4 val = *(const float4*)(z + (size_t)rr * 64 + 32 + v4 * 4);
        *(float4*)(out + (size_t)rr * 64 + v4 * 4) = val;
    }

    // ---- z2c fragments (fp16, persist): the B operand ---------------------
    // B[k=(q*8+j)][n=cc] = z2c[row cc][k]
    half8 a0, a1;
    {
        const float* zr = z + (size_t)(row_base + cc) * 64 + 32;
        float4 v0 = *(const float4*)(zr + q * 8);
        float4 v1 = *(const float4*)(zr + q * 8 + 4);
        a0[0]=(_Float16)v0.x; a0[1]=(_Float16)v0.y;
        a0[2]=(_Float16)v0.z; a0[3]=(_Float16)v0.w;
        a0[4]=(_Float16)v1.x; a0[5]=(_Float16)v1.y;
        a0[6]=(_Float16)v1.z; a0[7]=(_Float16)v1.w;
        if (q < 2) {
            const float* cr = c + (size_t)(row_base + cc) * 16 + q * 8;
            float4 u0 = *(const float4*)cr;
            float4 u1 = *(const float4*)(cr + 4);
            a1[0]=(_Float16)u0.x; a1[1]=(_Float16)u0.y;
            a1[2]=(_Float16)u0.z; a1[3]=(_Float16)u0.w;
            a1[4]=(_Float16)u1.x; a1[5]=(_Float16)u1.y;
            a1[6]=(_Float16)u1.z; a1[7]=(_Float16)u1.w;
        } else {
            #pragma unroll
            for (int j = 0; j < 8; ++j) a1[j] = (_Float16)0.0f;
            if (q == 2) a1[0] = (_Float16)1.0f;   // k=48 bias row
        }
    }

    // z1 base for this lane's spline inputs: z[row cc][n = g*4 + q]
    const float* z1p = z + (size_t)(row_base + cc) * 64 + q;

    float pv[33];

    // ---- prologue: GEMM group 0 -> LDS -> pv registers (one exposed chain)
    GEMM_GROUP(0);
    READ_PV();

    float ld_acc = 0.0f;

    // ---- pipelined main loop: GEMM(g+1) overlaps spline(g) ----------------
    #pragma unroll 1
    for (int g = 0; g < NITER - 1; ++g) {
        const float in_g = z1p[g * 4];   // hot L1/L2 line; issues early
        GEMM_GROUP(g + 1);               // loads+MFMA+ds_write, independent of pv
        SPLINE(g, in_g);                 // pure VALU from registers, hides GEMM
        READ_PV();                       // after writes (in-order DS); latency
                                         // hides under next iter's GEMM issue
    }
    {
        const float in_l = z1p[(NITER - 1) * 4];
        SPLINE(NITER - 1, in_l);
    }

    // ---- logdet: lanes {cc, cc+16, cc+32, cc+48} hold row cc's partials ---
    ld_acc += __shfl_down(ld_acc, 32, 64);
    ld_acc += __shfl_down(ld_acc, 16, 64);
    if (q == 0)
        out[(size_t)M_ROWS * 64 + row_base + cc] = ld_acc;
}

extern "C" void kernel_launch(void* const* d_in, const int* in_sizes, int n_in,
                              void* d_out, int out_size, void* d_ws, size_t ws_size,
                              hipStream_t stream) {
    const float* c = (const float*)d_in[0];   // (M, 16)
    const float* z = (const float*)d_in[1];   // (M, 64)
    const float* W = (const float*)d_in[2];   // (48, 1056)
    const float* b = (const float*)d_in[3];   // (1056,)
    float* out = (float*)d_out;               // M*64 (x) then M (logdet)
    _Float16* WH = (_Float16*)d_ws;           // 98304 fp16 = 192 KiB

    pack_W<<<WB_ELEMS / 256, 256, 0, stream>>>(W, b, WH);
    fused_kernel<<<M_ROWS / BM, 256, 0, stream>>>(z, c, WH, out);
}